// Round 2
// baseline (189.270 us; speedup 1.0000x reference)
//
#include <hip/hip_runtime.h>

#define T_DIM 512
#define B_DIM 8192
#define GB 16      // batch columns per block
#define NC 64      // time chunks per block
#define LC 8       // timesteps per chunk (NC*LC == T_DIM)
#define BLOCK (GB * NC)   // 1024 threads
#define GRID (B_DIM / GB) // 512 blocks
#define GAMMA 0.99f

// V-trace + PPO loss, single fused kernel.
// Identities used (valid because RHO_THRESHOLD == C_THRESHOLD == 1):
//   adv_t    = p_t + m_t * carry,   p_t = rho*(r_t - v_t), m_t = gamma*rho*(1-d_t)
//   vtrace_t = v_t + adv_t          (next_v cancels everywhere except the t=T-1 init)
//   v_t - vtrace_t = -adv_t  =>  critic = 0.5*mean(adv^2)
// Per-thread state for the affine-scan replay is 3 floats per timestep:
//   rs = done ? -ratio : ratio  (sign encodes done), p, v.  LC=8 -> 24 floats,
//   register-resident under the 64-VGPR cap from __launch_bounds__(1024, 8).
__launch_bounds__(BLOCK, 8)
__global__ void vtrace_main(const float* __restrict__ prob,
                            const float* __restrict__ aprob,
                            const float* __restrict__ v,
                            const float* __restrict__ nv,
                            const float* __restrict__ rw,
                            const int* __restrict__ act,
                            const int* __restrict__ dnn,
                            float* __restrict__ ws,
                            float* __restrict__ out) {
    __shared__ float Sc[NC][GB];
    __shared__ float Mc[NC][GB];
    __shared__ float Cin[NC][GB];
    __shared__ float red[32];

    const int tid = threadIdx.x;
    const int bl  = tid & (GB - 1);
    const int c   = tid >> 4;          // chunk 0..NC-1
    const int b   = blockIdx.x * GB + bl;
    const int t0  = c * LC;

    float rsA[LC], pA[LC], vA[LC];
    float S = 0.0f, M = 1.0f;

    const float2* __restrict__ prob2  = (const float2*)prob;
    const float2* __restrict__ aprob2 = (const float2*)aprob;

#pragma unroll
    for (int i = LC - 1; i >= 0; --i) {
        const size_t idx = (size_t)(t0 + i) * B_DIM + b;
        float2 pr = prob2[idx];
        float2 qr = aprob2[idx];
        float vv  = v[idx];
        float rr  = rw[idx];
        int   a   = act[idx];
        int   d   = dnn[idx];

        float pa    = a ? pr.y : pr.x;
        float qa    = a ? qr.y : qr.x;
        // ratio = exp(logp - logp_act) == (pa/sum_p) / (qa/sum_q)
        float ratio = (pa * (qr.x + qr.y)) / ((pr.x + pr.y) * qa);
        float rho   = fminf(ratio, 1.0f);
        float m     = d ? 0.0f : GAMMA * rho;
        float p     = rho * (rr - vv);

        rsA[i] = d ? -ratio : ratio;
        pA[i]  = p;
        vA[i]  = vv;
        // compose F_t(x) = (v+p) + m*x in front of running composite
        S = (vv + p) + m * S;
        M = m * M;
    }

    Sc[c][bl] = S;
    Mc[c][bl] = M;
    __syncthreads();

    // serial cross-chunk suffix scan (reverse over time), one thread per b
    if (tid < GB) {
        float carry = nv[(size_t)(T_DIM - 1) * B_DIM + blockIdx.x * GB + tid];
        for (int cc = NC - 1; cc >= 0; --cc) {
            Cin[cc][tid] = carry;                 // carry entering chunk cc
            carry = Sc[cc][tid] + Mc[cc][tid] * carry;
        }
    }
    __syncthreads();

    // phase B: replay chunk from registers with corrected carry
    float carry  = Cin[c][bl];
    float critic = 0.0f, msum = 0.0f;
#pragma unroll
    for (int i = LC - 1; i >= 0; --i) {
        float rs  = rsA[i];
        float r_  = fabsf(rs);
        float m   = (rs > 0.0f) ? GAMMA * fminf(r_, 1.0f) : 0.0f;
        float adv = pA[i] + m * carry;
        carry     = adv + vA[i];                  // vtrace_t
        critic += adv * adv;
        float rc = fminf(fmaxf(r_, 0.8f), 1.2f);  // clip(ratio, 1 +/- 0.2)
        msum += fminf(r_ * adv, rc * adv);
    }

    // block reduction: wave64 shuffle, then cross-wave via LDS
#pragma unroll
    for (int off = 32; off > 0; off >>= 1) {
        critic += __shfl_down(critic, off, 64);
        msum   += __shfl_down(msum, off, 64);
    }
    const int wave = tid >> 6;                    // 0..15
    if ((tid & 63) == 0) { red[wave] = critic; red[16 + wave] = msum; }
    __syncthreads();

    if (tid == 0) {
        float cs = 0.0f, ms = 0.0f;
#pragma unroll
        for (int w = 0; w < 16; ++w) { cs += red[w]; ms += red[16 + w]; }
        // device-scope accumulation + ticket; ws[0..1] and counter are
        // zeroed by hipMemsetAsync in kernel_launch before this kernel.
        atomicAdd(&ws[0], cs);
        atomicAdd(&ws[1], ms);
        __threadfence();
        unsigned* cnt = (unsigned*)(ws + 2);
        unsigned ticket = atomicAdd(cnt, 1u);
        if (ticket == GRID - 1) {
            __threadfence();
            float c_tot = atomicAdd(&ws[0], 0.0f);  // atomic read-back
            float m_tot = atomicAdd(&ws[1], 0.0f);
            const float invN = 1.0f / (float)((size_t)T_DIM * B_DIM);
            out[0] = 0.5f * c_tot * invN - m_tot * invN;
        }
    }
}

extern "C" void kernel_launch(void* const* d_in, const int* in_sizes, int n_in,
                              void* d_out, int out_size, void* d_ws, size_t ws_size,
                              hipStream_t stream) {
    const float* prob  = (const float*)d_in[0];
    const float* aprob = (const float*)d_in[1];
    const float* v     = (const float*)d_in[2];
    const float* nv    = (const float*)d_in[3];
    const float* rw    = (const float*)d_in[4];
    const int*   act   = (const int*)d_in[5];
    const int*   dnn   = (const int*)d_in[6];
    float* ws  = (float*)d_ws;
    float* out = (float*)d_out;

    hipMemsetAsync(ws, 0, 12, stream);  // ws[0], ws[1], counter
    vtrace_main<<<GRID, BLOCK, 0, stream>>>(prob, aprob, v, nv, rw, act, dnn,
                                            ws, out);
}